// Round 7
// baseline (69.378 us; speedup 1.0000x reference)
//
#include <hip/hip_runtime.h>
#include <cstdio>

#define BB 2
#define TT 8
#define NNODE 5000
#define KK1 17
#define HH 4
#define NT (BB*TT*NNODE)          // 80000 (b,t,n) nodes
#define NSLICE 16                 // BB*TT
#define NREST (BB*7*NNODE)        // 70000 (b,t<7,n) rows for d_w

typedef unsigned short u16;
typedef unsigned int u32;

__device__ __forceinline__ u16 f2bf(float x) {
  u32 u = __float_as_uint(x);
  u32 r = (u + 0x7fffu + ((u >> 16) & 1u)) >> 16;  // RNE
  return (u16)r;
}
__device__ __forceinline__ float bfLo(u32 w){ return __uint_as_float(w << 16); }
__device__ __forceinline__ float bfHi(u32 w){ return __uint_as_float(w & 0xffff0000u); }

// ---------------------------------------------------------------------------
// k_prep: feat[m=(bt,n)][64] f32 -> node-major transposed bf16 staging:
//   gT [n][bt][64], a8T [n][bt][32], b8T [n][bt][32]
__global__ void __launch_bounds__(256) k_prep(
    const float* __restrict__ feat, const float* __restrict__ mm,
    const float* __restrict__ q1, const float* __restrict__ q2,
    u16* __restrict__ gT, u16* __restrict__ a8T, u16* __restrict__ b8T) {
  const int lane = threadIdx.x & 63;
  const int h = lane >> 4, i = lane & 15;
  const int bid = blockIdx.x;
  const int x = bid & 7;                                   // XCD
  const int local = (bid >> 3) * 4 + (threadIdx.x >> 6);   // 0..999 per XCD
  const int mbase = x * 10000 + local * 10;
  float Mrow[16], Qrow[16];
  const float* qsrc = (i < 8) ? (q1 + (h*8 + i)*16) : (q2 + (h*8 + (i - 8))*16);
#pragma unroll
  for (int j = 0; j < 16; ++j) {
    Mrow[j] = mm[(h*16 + i)*16 + j];
    Qrow[j] = qsrc[j];
  }
#pragma unroll 2
  for (int l = 0; l < 10; ++l) {
    const int m = mbase + l;
    const int off = local*10 + l;                 // 0..9999 within the 2-slice band
    const int bt = 2*x + (off >= NNODE);
    const int n = m - bt*NNODE;
    const float4* fp = reinterpret_cast<const float4*>(feat + (size_t)m*64 + h*16);
    float fv[16];
#pragma unroll
    for (int q = 0; q < 4; ++q) {
      float4 v = fp[q];
      fv[q*4+0] = v.x; fv[q*4+1] = v.y; fv[q*4+2] = v.z; fv[q*4+3] = v.w;
    }
    float accG = 0.f, accQ = 0.f;
#pragma unroll
    for (int j = 0; j < 16; ++j) {
      accG = fmaf(Mrow[j], fv[j], accG);
      accQ = fmaf(Qrow[j], fv[j], accQ);
    }
    gT[(size_t)n*1024 + bt*64 + lane] = f2bf(accG);
    if (i < 8) a8T[(size_t)n*512 + bt*32 + h*8 + i] = f2bf(accQ);
    else       b8T[(size_t)n*512 + bt*32 + h*8 + (i - 8)] = f2bf(accQ);
  }
}

// ---------------------------------------------------------------------------
// k_deg2: block = 1 node, 4 waves. lane=(bt,h); wave kq handles k=4kq..4kq+3.
// All gathers wave-uniform-base + lane-contiguous (coalesced 2KB blocks).
// deg reduction is the per-lane k-loop; cross-wave combine via tiny LDS.
// Writes wstage f32 [n][16k][bt][4h] and degT f32 [n][bt][4h].
__global__ void __launch_bounds__(256) k_deg2(
    const u16* __restrict__ gT, const int* __restrict__ nn,
    float* __restrict__ degT, float* __restrict__ wstage) {
  __shared__ float red[4][64];
  const int n = blockIdx.x;
  const int lane = threadIdx.x & 63;
  const int kq = __builtin_amdgcn_readfirstlane(threadIdx.x >> 6);  // 0..3
  const int bt = lane >> 2;   // 0..15
  const int h  = lane & 3;
  // own row (bt,h) of node n
  const uint4* po = reinterpret_cast<const uint4*>(gT + (size_t)n*1024 + bt*64 + h*16);
  uint4 A0 = po[0], A1 = po[1];
  u32 aw[8] = {A0.x,A0.y,A0.z,A0.w,A1.x,A1.y,A1.z,A1.w};
  float av[16];
  float si = 0.f;
#pragma unroll
  for (int r = 0; r < 8; ++r) {
    av[2*r]   = bfLo(aw[r]);
    av[2*r+1] = bfHi(aw[r]);
    si = fmaf(av[2*r], av[2*r], si);
    si = fmaf(av[2*r+1], av[2*r+1], si);
  }
  float dsum = 0.f;
#pragma unroll
  for (int kk = 0; kk < 4; ++kk) {
    const int k = kq*4 + kk;
    int jr = nn[n*KK1 + 1 + k];          // wave-uniform -> scalar load
    bool v = jr >= 0;
    int j = v ? jr : 0;
    const uint4* pj = reinterpret_cast<const uint4*>(gT + (size_t)j*1024 + bt*64 + h*16);
    uint4 B0 = pj[0], B1 = pj[1];
    u32 bw[8] = {B0.x,B0.y,B0.z,B0.w,B1.x,B1.y,B1.z,B1.w};
    float dot = 0.f, sj = 0.f;
#pragma unroll
    for (int r = 0; r < 8; ++r) {
      float bl = bfLo(bw[r]), bh = bfHi(bw[r]);
      dot = fmaf(av[2*r], bl, dot); dot = fmaf(av[2*r+1], bh, dot);
      sj  = fmaf(bl, bl, sj);       sj  = fmaf(bh, bh, sj);
    }
    float e = si + sj - 2.f*dot;
    float w = v ? __expf(-e) : 0.f;
    wstage[(size_t)n*1024 + k*64 + lane] = w;
    dsum += w;
  }
  red[kq][lane] = dsum;
  __syncthreads();
  if (kq == 0) {
    float d = red[0][lane] + red[1][lane] + red[2][lane] + red[3][lane];
    degT[(size_t)n*64 + lane] = d;
  }
}

// ---------------------------------------------------------------------------
// k_uw2: block = 1 node. Normalize w by rsqrt(deg_i*deg_j); LDS transpose;
// coalesced 256B-chunk stores into u_w [bt][n][k*4+h].
__global__ void __launch_bounds__(256) k_uw2(
    const float* __restrict__ wstage, const int* __restrict__ nn,
    const float* __restrict__ degT, float* __restrict__ uw) {
  __shared__ float outl[16*72];                 // [k][lane], pad 72
  const int n = blockIdx.x;
  const int lane = threadIdx.x & 63;
  const int kq = __builtin_amdgcn_readfirstlane(threadIdx.x >> 6);
  float di = degT[(size_t)n*64 + lane];
#pragma unroll
  for (int kk = 0; kk < 4; ++kk) {
    const int k = kq*4 + kk;
    int jr = nn[n*KK1 + 1 + k];
    int j = (jr >= 0) ? jr : 0;
    float dj = degT[(size_t)j*64 + lane];
    float w  = wstage[(size_t)n*1024 + k*64 + lane];
    float p = di * dj;
    outl[k*72 + lane] = (p > 0.f) ? w * rsqrtf(p) : 0.f;
  }
  __syncthreads();
  // store: thread c -> bt=c>>4, q=c&15: float4 = outl[q*72 + bt*4 .. +3]
  const int c = threadIdx.x;
  const int bt = c >> 4, q = c & 15;
  float4 val = *reinterpret_cast<const float4*>(&outl[q*72 + bt*4]);
  float4* ob = reinterpret_cast<float4*>(uw);
  ob[(size_t)bt*80000 + n*16 + q] = val;
}

// ---------------------------------------------------------------------------
// k_dw2: block = 4 nodes (wave = node). lane=(btv,h), btv<14 active.
// Coalesced a8T gathers; 17-k loop; LDS transpose epilogue.
__global__ void __launch_bounds__(256) k_dw2(
    const u16* __restrict__ a8T, const u16* __restrict__ b8T,
    const int* __restrict__ nn, float* __restrict__ dw) {
  __shared__ float lds[4*14*68];                // [wv][btr][68]
  const int wv = __builtin_amdgcn_readfirstlane(threadIdx.x >> 6);
  const int n = blockIdx.x*4 + wv;
  const int lane = threadIdx.x & 63;
  const int btv = lane >> 2;                    // 0..15
  const int h = lane & 3;
  const bool alive = btv < 14;
  const int btc = alive ? btv : 0;
  const int b = btc / 7, t = btc % 7;
  // own b8 row: node n, slice (b, t+1)
  uint4 Bv = *reinterpret_cast<const uint4*>(b8T + (size_t)n*512 + (b*8 + t + 1)*32 + h*8);
  float bv[8] = {bfLo(Bv.x), bfHi(Bv.x), bfLo(Bv.y), bfHi(Bv.y),
                 bfLo(Bv.z), bfHi(Bv.z), bfLo(Bv.w), bfHi(Bv.w)};
  const int bta = b*8 + t;                      // a-side slice
  float wk[17];
  float indeg = 0.f;
#pragma unroll
  for (int k = 0; k < KK1; ++k) {
    int jr = nn[n*KK1 + k];                     // wave-uniform -> scalar
    bool v = jr >= 0;
    int j = v ? jr : 0;
    uint4 Av = *reinterpret_cast<const uint4*>(a8T + (size_t)j*512 + bta*32 + h*8);
    float dot = 0.f;
    dot = fmaf(bfLo(Av.x), bv[0], dot); dot = fmaf(bfHi(Av.x), bv[1], dot);
    dot = fmaf(bfLo(Av.y), bv[2], dot); dot = fmaf(bfHi(Av.y), bv[3], dot);
    dot = fmaf(bfLo(Av.z), bv[4], dot); dot = fmaf(bfHi(Av.z), bv[5], dot);
    dot = fmaf(bfLo(Av.w), bv[6], dot); dot = fmaf(bfHi(Av.w), bv[7], dot);
    float w = v ? __expf(-dot) : 0.f;
    wk[k] = w;
    indeg += w;
  }
  float inv = (indeg > 0.f) ? (1.0f / indeg) : 0.f;
  if (alive) {
#pragma unroll
    for (int k = 0; k < KK1; ++k) lds[(wv*14 + btv)*68 + k*4 + h] = wk[k] * inv;
  }
  __syncthreads();
  // epilogue: 4 nodes x 14 rows x 17 float4 = 952 chunks by 256 threads
  const int n0 = blockIdx.x*4;
  for (int c = threadIdx.x; c < 4*14*17; c += 256) {
    const int row = c / 17;                     // wv*14 + btr
    const int col = (c % 17) * 4;
    const int wvv = row / 14, btr = row % 14;
    float4 val = *reinterpret_cast<const float4*>(&lds[row*68 + col]);
    *reinterpret_cast<float4*>(dw + ((size_t)btr*NNODE + n0 + wvv)*68 + col) = val;
  }
}

extern "C" void kernel_launch(void* const* d_in, const int* in_sizes, int n_in,
                              void* d_out, int out_size, void* d_ws, size_t ws_size,
                              hipStream_t stream) {
  const float* feat = (const float*)d_in[0];
  const int*   nn   = (const int*)d_in[1];
  const float* q1   = (const float*)d_in[2];
  const float* q2   = (const float*)d_in[3];
  const float* mm   = (const float*)d_in[4];
  float* uw = (float*)d_out;
  float* dw = uw + (size_t)NT*64;                 // 5,120,000 elems in

  const size_t GT_BYTES = (size_t)NNODE*1024*2;   // 10,240,000
  const size_t AT_BYTES = (size_t)NNODE*512*2;    //  5,120,000 each
  const size_t DG_BYTES = (size_t)NNODE*64*4;     //  1,280,000
  const size_t WS_BYTES = (size_t)NNODE*1024*4;   // 20,480,000
  const size_t NEED = GT_BYTES + 2*AT_BYTES + DG_BYTES + WS_BYTES;  // 42.24 MB
  if (ws_size < NEED) {
    fprintf(stderr, "kernel_launch: ws_size %zu < needed %zu\n", ws_size, NEED);
    return;
  }
  u16*   gT   = (u16*)d_ws;
  u16*   a8T  = (u16*)((char*)d_ws + GT_BYTES);
  u16*   b8T  = (u16*)((char*)d_ws + GT_BYTES + AT_BYTES);
  float* degT = (float*)((char*)d_ws + GT_BYTES + 2*AT_BYTES);
  float* wst  = (float*)((char*)d_ws + GT_BYTES + 2*AT_BYTES + DG_BYTES);

  k_prep<<<2000, 256, 0, stream>>>(feat, mm, q1, q2, gT, a8T, b8T);
  k_deg2<<<NNODE, 256, 0, stream>>>(gT, nn, degT, wst);
  k_uw2 <<<NNODE, 256, 0, stream>>>(wst, nn, degT, uw);
  k_dw2 <<<NNODE/4, 256, 0, stream>>>(a8T, b8T, nn, dw);
}